// Round 10
// baseline (296.633 us; speedup 1.0000x reference)
//
#include <hip/hip_runtime.h>

// Problem constants (from reference): F=50000, K=32, E=128, N=100000
#define F_TOTAL 50000
#define N_NODE  100000
#define KNBR    32
#define EMB     128
#define FB      16      // f-rows per block (3125 * 16 == 50000 exactly)
#define RPW     4       // rows per wave (4 waves * 4 = 16)

// ---------------------------------------------------------------------------
// Kernel 1: y[n] = embi[n] . u   (rank-1 score is f-independent)
// ---------------------------------------------------------------------------
__global__ __launch_bounds__(256)
void node_scores(const float* __restrict__ embi,
                 const float* __restrict__ u,
                 float*       __restrict__ y)
{
    const int wave = threadIdx.x >> 6;
    const int lane = threadIdx.x & 63;
    const float2 uv = *(const float2*)(u + 2 * lane);

    const int base = (blockIdx.x * 4 + wave) * 8;

    float v[8];
#pragma unroll
    for (int j = 0; j < 8; ++j) {
        const float2 e = *(const float2*)(embi + (size_t)(base + j) * EMB + 2 * lane);
        v[j] = e.x * uv.x + e.y * uv.y;
    }

#pragma unroll
    for (int bit = 4; bit >= 1; bit >>= 1) {
        const bool upper = (lane & bit) != 0;
#pragma unroll
        for (int j = 0; j < bit; ++j) {
            const float send = upper ? v[j] : v[j + bit];
            const float recv = __shfl_xor(send, bit);
            v[j] = (upper ? v[j + bit] : v[j]) + recv;
        }
    }
    float d = v[0];
    d += __shfl_xor(d, 8);
    d += __shfl_xor(d, 16);
    d += __shfl_xor(d, 32);   // full 64-lane sum for row base + (lane&7)

    if (lane < 8) y[base + lane] = d;
}

// ---------------------------------------------------------------------------
// Kernel 2: attention aggregate, LDS-free.
// r9 lesson: wave serial time = (#gather phases) x fill-latency; was 4 rows
// x 4 phases = 16 round-trips/wave (block dur 9.4us matches). This version:
//   - all 4 rows' y-gather + softmax hoisted to a front phase (out of the
//     gather critical path),
//   - chunk 8 -> 16: 2 phases/row => 8 round-trips/wave (2x fewer),
//   - __launch_bounds__(256,8) pins VGPR cap at 64 (8 waves/SIMD boundary).
// ---------------------------------------------------------------------------
__global__ __launch_bounds__(256, 8)
void attn_agg(const int*   __restrict__ adj,    // [F,K] int32
              const float* __restrict__ embi,   // [N,E]
              const float* __restrict__ y,      // [N] precomputed scores
              float*       __restrict__ agg)    // [F,E] == d_out
{
    const int wave  = threadIdx.x >> 6;
    const int lane  = threadIdx.x & 63;
    const int fbase = blockIdx.x * FB;

    // ---- front phase: indices + normalized weights for all 4 rows ----
    int   idx[RPW];
    float an[RPW];
#pragma unroll
    for (int i = 0; i < RPW; ++i) {
        const int f = fbase + wave * RPW + i;
        idx[i] = adj[f * KNBR + (lane & 31)];   // lane holds k = lane&31
    }
#pragma unroll
    for (int i = 0; i < RPW; ++i) {
        // y is 400KB -> L2-resident; 4 independent gathers in flight
        float alpha = y[idx[i]] + ((idx[i] != 0) ? 0.0f : -10000.0f);
        float mx = alpha;
#pragma unroll
        for (int bit = 1; bit <= 16; bit <<= 1)
            mx = fmaxf(mx, __shfl_xor(mx, bit));
        const float e = __expf(alpha - mx);
        float s = e;
#pragma unroll
        for (int bit = 1; bit <= 16; bit <<= 1)
            s += __shfl_xor(s, bit);
        an[i] = e / s;                           // weight for k = lane&31
    }

    // ---- gather + accumulate: 2 phases of 16 rows each ----
#pragma unroll
    for (int i = 0; i < RPW; ++i) {
        const int f = fbase + wave * RPW + i;
        float2 acc = make_float2(0.f, 0.f);
#pragma unroll
        for (int c = 0; c < 2; ++c) {
            float2 nb[16];
#pragma unroll
            for (int j = 0; j < 16; ++j) {
                const unsigned ik =
                    (unsigned)__builtin_amdgcn_readlane(idx[i], c * 16 + j);
                nb[j] = *(const float2*)(embi + (size_t)ik * EMB + 2 * lane);
            }
#pragma unroll
            for (int j = 0; j < 16; ++j) {
                const float a = __uint_as_float((unsigned)__builtin_amdgcn_readlane(
                    (int)__float_as_uint(an[i]), c * 16 + j));
                acc.x = fmaf(a, nb[j].x, acc.x);
                acc.y = fmaf(a, nb[j].y, acc.y);
            }
        }
        *(float2*)(agg + (size_t)f * EMB + 2 * lane) = acc;
    }
}

// ---------------------------------------------------------------------------
// Kernel 3: gated fusion (unchanged from r9). Stages embf + agg (= out, in
// place) into LDS; gate GEMM: thread -> column pair, wave -> j-quarter,
// W (128KB) read once per block; LDS partial combine; in-place overwrite.
// ---------------------------------------------------------------------------
__global__ __launch_bounds__(256)
void gate_fuse(const float* __restrict__ embf,   // [F,E]
               const float* __restrict__ W,      // [E,2E]
               const float* __restrict__ bias,   // [E]
               float*       __restrict__ out)    // [F,E]: in = agg, out = result
{
    __shared__ float catbuf[FB][2 * EMB];  // 16 KB
    __shared__ float pbuf[FB][EMB];        //  8 KB

    const int tid   = threadIdx.x;
    const int fbase = blockIdx.x * FB;

#pragma unroll
    for (int q = 0; q < 2; ++q) {
        const int idx = q * 256 + tid;     // 0..511
        const int r   = idx >> 5;          // 32 float4 per row
        const int c   = (idx & 31) * 4;
        *(float4*)&catbuf[r][c] =
            *(const float4*)(embf + (size_t)(fbase + r) * EMB + c);
        *(float4*)&catbuf[r][EMB + c] =
            *(const float4*)(out + (size_t)(fbase + r) * EMB + c);
    }
    __syncthreads();

    const int p  = tid & 63;
    const int g  = tid >> 6;       // wave index (divergence is wave-uniform)
    const int c0 = 2 * p, c1 = c0 + 1;
    const int jbase = g * 64;

    float acc0[FB], acc1[FB];
#pragma unroll
    for (int r = 0; r < FB; ++r) { acc0[r] = 0.f; acc1[r] = 0.f; }

    const float* W0 = W + (size_t)c0 * (2 * EMB) + jbase;
    const float* W1 = W + (size_t)c1 * (2 * EMB) + jbase;

#pragma unroll 4
    for (int j = 0; j < 64; j += 4) {
        const float4 w0 = *(const float4*)(W0 + j);
        const float4 w1 = *(const float4*)(W1 + j);
#pragma unroll
        for (int r = 0; r < FB; ++r) {
            const float4 cv = *(const float4*)&catbuf[r][jbase + j];  // broadcast
            acc0[r] += cv.x * w0.x + cv.y * w0.y + cv.z * w0.z + cv.w * w0.w;
            acc1[r] += cv.x * w1.x + cv.y * w1.y + cv.z * w1.z + cv.w * w1.w;
        }
    }

    if (g == 3) {
#pragma unroll
        for (int r = 0; r < FB; ++r) { pbuf[r][c0] = acc0[r]; pbuf[r][c1] = acc1[r]; }
    }
    __syncthreads();
    if (g == 2) {
#pragma unroll
        for (int r = 0; r < FB; ++r) { pbuf[r][c0] += acc0[r]; pbuf[r][c1] += acc1[r]; }
    }
    __syncthreads();
    if (g == 1) {
#pragma unroll
        for (int r = 0; r < FB; ++r) { pbuf[r][c0] += acc0[r]; pbuf[r][c1] += acc1[r]; }
    }
    __syncthreads();
    if (g == 0) {
        const float2 bv = *(const float2*)(bias + c0);
#pragma unroll
        for (int r = 0; r < FB; ++r) {
            const float t0 = acc0[r] + pbuf[r][c0] + bv.x;
            const float t1 = acc1[r] + pbuf[r][c1] + bv.y;
            const float g0 = 1.f / (1.f + __expf(-t0));
            const float g1 = 1.f / (1.f + __expf(-t1));
            const float e0 = catbuf[r][c0],       e1 = catbuf[r][c1];
            const float a0 = catbuf[r][EMB + c0], a1 = catbuf[r][EMB + c1];
            float2 o;
            o.x = g0 * e0 + (1.f - g0) * a0;
            o.y = g1 * e1 + (1.f - g1) * a1;
            *(float2*)(out + (size_t)(fbase + r) * EMB + c0) = o;
        }
    }
}

extern "C" void kernel_launch(void* const* d_in, const int* in_sizes, int n_in,
                              void* d_out, int out_size, void* d_ws, size_t ws_size,
                              hipStream_t stream) {
    const int*   adj  = (const int*)  d_in[0];  // adjacency_fi [F,K] int32
    const float* embi = (const float*)d_in[1];  // embedding_i [N,E]
    const float* embf = (const float*)d_in[2];  // embedding_f_weight [F,E]
    const float* u    = (const float*)d_in[3];  // u [E,1]
    const float* W    = (const float*)d_in[4];  // W_weight [E,2E]
    const float* bias = (const float*)d_in[5];  // W_bias [E]
    float* outp = (float*)d_out;
    float* y    = (float*)d_ws;                 // N_NODE floats (400 KB scratch)

    node_scores<<<3125, 256, 0, stream>>>(embi, u, y);
    attn_agg  <<<F_TOTAL / FB, 256, 0, stream>>>(adj, embi, y, outp);
    gate_fuse <<<F_TOTAL / FB, 256, 0, stream>>>(embf, W, bias, outp);
}